// Round 7
// baseline (1598.822 us; speedup 1.0000x reference)
//
#include <hip/hip_runtime.h>
#include <hip/hip_bf16.h>
#include <math.h>

// Problem constants
#define Bn   64
#define Ssz  512     // W*H = 64*8
#define Ed   192
#define NHd  6
#define HDd  32
#define Ld   6
#define COd  256
#define Himg 8
#define Wimg 64
#define Mrows (Bn*Ssz)   // 32768

typedef unsigned int  uint;
typedef unsigned short ushort;
using short8 = __attribute__((ext_vector_type(8))) short;
using f32x4  = __attribute__((ext_vector_type(4))) float;

#define WAIT_LGKM() __asm__ __volatile__("s_waitcnt lgkmcnt(0)" ::: "memory")

__device__ inline ushort f2b(float f) {          // fp32 -> bf16 RNE
    uint u = __builtin_bit_cast(uint, f);
    u = (u + 0x7FFFu + ((u >> 16) & 1u)) >> 16;
    return (ushort)u;
}

__device__ __forceinline__ float fexp2(float x) {
#if __has_builtin(__builtin_amdgcn_exp2f)
    return __builtin_amdgcn_exp2f(x);
#else
    return exp2f(x);
#endif
}

// ---------------------------------------------------------------------------
// reshape: image [B, E, 8, 64] -> X [B, S=w*8+h, E]  (fp32)
__global__ __launch_bounds__(256) void reshape_in(const float* __restrict__ img,
                                                  float* __restrict__ X) {
    int t = blockIdx.x * 256 + threadIdx.x;
    int c = t % Ed;
    int s = (t / Ed) % Ssz;
    int b = t / (Ed * Ssz);
    int w = s >> 3, h = s & 7;
    X[t] = img[(((size_t)b * Ed + c) * Himg + h) * Wimg + w];
}

// ---------------------------------------------------------------------------
__global__ __launch_bounds__(256) void f2b_arr(const float* __restrict__ in,
                                               ushort* __restrict__ out, int n) {
    int t = blockIdx.x * 256 + threadIdx.x;
    if (t < n) out[t] = f2b(in[t]);
}

// conv_w [CO,E,3,1] -> bf16 layout [co][kh*192+c]
__global__ __launch_bounds__(256) void conv_w_to_bf16(const float* __restrict__ cw,
                                                      ushort* __restrict__ out) {
    int t = blockIdx.x * 256 + threadIdx.x;
    if (t >= COd * 576) return;
    int co = t / 576, rem = t % 576;
    int kh = rem / Ed, c = rem % Ed;
    out[t] = f2b(cw[((size_t)co * Ed + c) * 3 + kh]);
}

// ---------------------------------------------------------------------------
// LayerNorm over E=192, one wave per row, lanes 0..47 hold float4 each.
__global__ __launch_bounds__(256) void ln_kernel(const float* __restrict__ in,
                                                 float* __restrict__ out,
                                                 ushort* __restrict__ outb,
                                                 const float* __restrict__ g,
                                                 const float* __restrict__ bb) {
    int row  = blockIdx.x * 4 + (threadIdx.x >> 6);
    int lane = threadIdx.x & 63;
    bool act = lane < 48;
    float4 v = make_float4(0.f, 0.f, 0.f, 0.f);
    if (act) v = ((const float4*)(in + (size_t)row * Ed))[lane];
    float s = v.x + v.y + v.z + v.w;
    #pragma unroll
    for (int off = 32; off > 0; off >>= 1) s += __shfl_xor(s, off);
    float mu = s * (1.f / 192.f);
    float4 d = make_float4(v.x - mu, v.y - mu, v.z - mu, v.w - mu);
    float qv = act ? (d.x*d.x + d.y*d.y + d.z*d.z + d.w*d.w) : 0.f;
    #pragma unroll
    for (int off = 32; off > 0; off >>= 1) qv += __shfl_xor(qv, off);
    float rstd = rsqrtf(qv * (1.f / 192.f) + 1e-5f);
    if (act) {
        float4 gg  = ((const float4*)g)[lane];
        float4 bbv = ((const float4*)bb)[lane];
        float4 y = make_float4(d.x * rstd * gg.x + bbv.x,
                               d.y * rstd * gg.y + bbv.y,
                               d.z * rstd * gg.z + bbv.z,
                               d.w * rstd * gg.w + bbv.w);
        ((float4*)(out + (size_t)row * Ed))[lane] = y;
        ushort4 yb;
        yb.x = f2b(y.x); yb.y = f2b(y.y); yb.z = f2b(y.z); yb.w = f2b(y.w);
        *(ushort4*)(outb + (size_t)row * Ed + lane * 4) = yb;
    }
}

// ---------------------------------------------------------------------------
// Register-resident bf16 MFMA GEMM: no LDS, no barriers. One wave owns a
// 64x64 output tile; A frags (4 msub x 6 ksub) live in VGPRs; B frags stream
// global->VGPR per nsub. K = KCHUNKS*192. Coalesced: each frag load = 16 rows
// x 64 B. Loads for nsub+1 overlap MFMAs of nsub via compiler vmcnt schedule.
// VOUT: Q cols -> QP[bh][s][32], K cols -> KP[bh][s][32], V cols -> VT[bh][d][s].
template<int KCHUNKS, int RELU, int RESID, int OBF, int VOUT>
__global__ __launch_bounds__(256, 2) void gemm_reg(
    const ushort* __restrict__ A, const ushort* __restrict__ Wt,
    const float* __restrict__ bias, const float* __restrict__ resid,
    float* __restrict__ C, ushort* __restrict__ Cb,
    ushort* __restrict__ qpout, ushort* __restrict__ kpout,
    ushort* __restrict__ vtout,
    int M, int N, int NCH)
{
    const int lane = threadIdx.x & 63;
    const int wid  = (blockIdx.x << 2) + (threadIdx.x >> 6);
    const int row0 = (wid / NCH) * 64;
    const int col0 = (wid % NCH) * 64;
    const int K = KCHUNKS * 192;
    const int g = lane >> 4, ql = lane & 15;

    f32x4 acc[4][4];
    #pragma unroll
    for (int i = 0; i < 4; ++i)
        #pragma unroll
        for (int j = 0; j < 4; ++j) acc[i][j] = (f32x4){0.f, 0.f, 0.f, 0.f};

    const ushort* Ab = A  + (size_t)(row0 + ql) * K + g * 8;
    const ushort* Bb = Wt + (size_t)(col0 + ql) * K + g * 8;

    for (int kc = 0; kc < KCHUNKS; ++kc) {
        short8 af[4][6];
        #pragma unroll
        for (int ms = 0; ms < 4; ++ms)
            #pragma unroll
            for (int ks = 0; ks < 6; ++ks)
                af[ms][ks] = *(const short8*)(Ab + (size_t)ms * 16 * K + kc * 192 + ks * 32);
        #pragma unroll
        for (int ns = 0; ns < 4; ++ns) {
            short8 bf[6];
            #pragma unroll
            for (int ks = 0; ks < 6; ++ks)
                bf[ks] = *(const short8*)(Bb + (size_t)ns * 16 * K + kc * 192 + ks * 32);
            #pragma unroll
            for (int ks = 0; ks < 6; ++ks)
                #pragma unroll
                for (int ms = 0; ms < 4; ++ms)
                    acc[ms][ns] = __builtin_amdgcn_mfma_f32_16x16x32_bf16(
                        af[ms][ks], bf[ks], acc[ms][ns], 0, 0, 0);
        }
    }

    #pragma unroll
    for (int ms = 0; ms < 4; ++ms) {
        #pragma unroll
        for (int ns = 0; ns < 4; ++ns) {
            int r0  = row0 + ms * 16 + g * 4;
            int col = col0 + ns * 16 + ql;
            float bvv = bias[col];
            float v[4];
            #pragma unroll
            for (int r = 0; r < 4; ++r) {
                v[r] = acc[ms][ns][r] + bvv;
                if (RELU) v[r] = fmaxf(v[r], 0.f);
                if (RESID) v[r] += resid[(size_t)(r0 + r) * N + col];
            }
            if (VOUT) {
                int bidx = r0 >> 9, srow = r0 & 511;
                if (col >= 384) {                 // V -> VT[bh][d][s]
                    int hh = (col - 384) >> 5, dd = (col - 384) & 31;
                    ushort4 pv;
                    pv.x = f2b(v[0]); pv.y = f2b(v[1]); pv.z = f2b(v[2]); pv.w = f2b(v[3]);
                    *(ushort4*)(vtout + (((size_t)(bidx * NHd + hh) * 32 + dd) << 9) + srow) = pv;
                } else {                          // Q/K -> {QP,KP}[bh][s][32]
                    ushort* dst = (col < 192) ? qpout : kpout;
                    int cc = (col < 192) ? col : col - 192;
                    int hh = cc >> 5, dd = cc & 31;
                    ushort* p = dst + ((size_t)(bidx * NHd + hh) << 14) + (size_t)srow * 32 + dd;
                    p[0]  = f2b(v[0]); p[32] = f2b(v[1]);
                    p[64] = f2b(v[2]); p[96] = f2b(v[3]);
                }
            } else {
                #pragma unroll
                for (int r = 0; r < 4; ++r) {
                    if (OBF) Cb[(size_t)(r0 + r) * N + col] = f2b(v[r]);
                    else     C [(size_t)(r0 + r) * N + col] = v[r];
                }
            }
        }
    }
}

// ---------------------------------------------------------------------------
// MFMA attention over packed per-head QP/KP[bh][s][32], VT[bh][d][s].
// Unshifted softmax via exp2 (scale*log2e folded); denominator computed by a
// ones-vector MFMA in the PV phase (lands on the owning row -> no shfl).
// One wave = 16 q x 512 keys; 4-chunk ILP groups, wave-private LDS P staging.
template<int USE_MASK>
__global__ __launch_bounds__(256) void attn_mfma(const ushort* __restrict__ qp,
                                                 const ushort* __restrict__ kp,
                                                 const ushort* __restrict__ vt,
                                                 ushort* __restrict__ att) {
    __shared__ __align__(16) ushort P[4][4][512];    // 16 KB: wave x chunk x frag
    const int bh = blockIdx.x;
    const int b = bh / NHd, h = bh % NHd;
    const int wave = threadIdx.x >> 6, lane = threadIdx.x & 63;
    const int g = lane >> 4, ql = lane & 15;
    const int q0 = blockIdx.y * 64 + wave * 16;      // q row in [0,512)
    const int sq = q0 + ql;
    const int qh = blockIdx.y;            // sq>>6 (block 64-aligned)
    const int qw = wave * 16 + ql;        // sq&63
    const float c2 = 0.2550547270628364f; // log2(e)/sqrt(32)

    const ushort* qbase = qp + ((size_t)bh << 14);
    const ushort* kbase = kp + ((size_t)bh << 14);
    const ushort* vbase = vt + ((size_t)bh << 14);
    short8 qf = *(const short8*)(qbase + (size_t)sq * 32 + g * 8);
    ushort* pw = &P[wave][0][0];

    short8 onesf;
    #pragma unroll
    for (int j = 0; j < 8; ++j) onesf[j] = (short)0x3F80;   // bf16 1.0

    // per-lane window masks for the two kw-base cases (multiplicative)
    float pm0[8], pm1[8];
    if (USE_MASK) {
        #pragma unroll
        for (int i = 0; i < 8; ++i) {
            int keyl = (i >> 2) * 16 + 4 * g + (i & 3);
            int dw0 = keyl - qw;      dw0 = dw0 < 0 ? -dw0 : dw0;
            int dw1 = keyl + 32 - qw; dw1 = dw1 < 0 ? -dw1 : dw1;
            pm0[i] = (dw0 <= 5) ? 0.f : 1.f;
            pm1[i] = (dw1 <= 5) ? 0.f : 1.f;
        }
    }

    f32x4 o0 = {0.f,0.f,0.f,0.f}, o1 = {0.f,0.f,0.f,0.f}, o2 = {0.f,0.f,0.f,0.f};
    const f32x4 z = {0.f,0.f,0.f,0.f};
    const int wst0 = ((g >> 1) * 16 + ql) * 8 + (g & 1) * 4;        // keys 4g..4g+3
    const int wst1 = (((g >> 1) + 2) * 16 + ql) * 8 + (g & 1) * 4;  // keys 16+4g..

    for (int grp = 0; grp < 4; ++grp) {
        #pragma unroll
        for (int c = 0; c < 4; ++c) {
            const int kt = grp * 4 + c;
            const int kb = kt * 32;
            short8 kf0 = *(const short8*)(kbase + (size_t)(kb + ql) * 32 + g * 8);
            short8 kf1 = *(const short8*)(kbase + (size_t)(kb + 16 + ql) * 32 + g * 8);
            f32x4 st0 = __builtin_amdgcn_mfma_f32_16x16x32_bf16(kf0, qf, z, 0, 0, 0);
            f32x4 st1 = __builtin_amdgcn_mfma_f32_16x16x32_bf16(kf1, qf, z, 0, 0, 0);
            float p[8];
            #pragma unroll
            for (int r = 0; r < 4; ++r) {
                p[r]     = fexp2(st0[r] * c2);
                p[4 + r] = fexp2(st1[r] * c2);
            }
            if (USE_MASK) {
                int dh = (kt >> 1) - qh; dh = dh < 0 ? -dh : dh;
                if (dh <= 3) {                       // wave-uniform branch
                    const float* pm = (kt & 1) ? pm1 : pm0;
                    #pragma unroll
                    for (int i = 0; i < 8; ++i) p[i] *= pm[i];
                }
            }
            uint u[8];
            #pragma unroll
            for (int i = 0; i < 8; ++i) u[i] = __builtin_bit_cast(uint, p[i]) + 0x8000u;
            uint2 w0, w1;
            w0.x = __builtin_amdgcn_perm(u[1], u[0], 0x07060302u);
            w0.y = __builtin_amdgcn_perm(u[3], u[2], 0x07060302u);
            w1.x = __builtin_amdgcn_perm(u[5], u[4], 0x07060302u);
            w1.y = __builtin_amdgcn_perm(u[7], u[6], 0x07060302u);
            *(uint2*)(pw + c * 512 + wst0) = w0;
            *(uint2*)(pw + c * 512 + wst1) = w1;
        }
        WAIT_LGKM();                              // P writes visible to own wave
        #pragma unroll
        for (int c = 0; c < 4; ++c) {
            const int kb = (grp * 4 + c) * 32;
            short8 paf = *(const short8*)(pw + c * 512 + lane * 8);
            short8 vf0 = *(const short8*)(vbase + (size_t)ql * 512 + kb + 8 * g);
            short8 vf1 = *(const short8*)(vbase + (size_t)(16 + ql) * 512 + kb + 8 * g);
            o0 = __builtin_amdgcn_mfma_f32_16x16x32_bf16(paf, vf0, o0, 0, 0, 0);
            o1 = __builtin_amdgcn_mfma_f32_16x16x32_bf16(paf, vf1, o1, 0, 0, 0);
            o2 = __builtin_amdgcn_mfma_f32_16x16x32_bf16(paf, onesf, o2, 0, 0, 0);
        }
        WAIT_LGKM();                              // reads done before overwrite
    }
    // o2[r] = sum_k P for q-row q0+4g+r (all cols identical)
    ushort* op = att + (size_t)b * Ssz * Ed + h * 32;
    #pragma unroll
    for (int r = 0; r < 4; ++r) {
        float iv = 1.f / o2[r];
        int row = q0 + 4 * g + r;
        op[(size_t)row * Ed + ql]      = f2b(o0[r] * iv);
        op[(size_t)row * Ed + 16 + ql] = f2b(o1[r] * iv);
    }
}

// ---------------------------------------------------------------------------
// im2col for merging conv: A2[r=(b*4+ho)*64+w][kh*192+c] = X[b, w*8+2ho+kh-1, c]
__global__ __launch_bounds__(256) void im2col(const float* __restrict__ X,
                                              ushort* __restrict__ A2) {
    int t = blockIdx.x * 256 + threadIdx.x;      // 9437184
    int col = t % 576;
    int r   = t / 576;
    int kh = col / Ed, c = col % Ed;
    int w = r & 63, ho = (r >> 6) & 3, b = r >> 8;
    int hin = 2 * ho + kh - 1;
    float v = 0.f;
    if (hin >= 0 && hin < Himg)
        v = X[((size_t)(b * Ssz + w * Himg + hin)) * Ed + c];
    A2[t] = f2b(v);
}

// ---------------------------------------------------------------------------
// channel LN on conv output C2[r=(b*4+ho)*64+w][co=256] -> out[b,co,ho,w]
__global__ __launch_bounds__(256) void ln_out_kernel(const float* __restrict__ C2,
                                                     const float* __restrict__ g,
                                                     const float* __restrict__ beta,
                                                     float* __restrict__ out) {
    __shared__ float lds[32 * 257];
    int w0 = blockIdx.x * 32, ho = blockIdx.y, b = blockIdx.z;
    int tid = threadIdx.x;
    size_t rbase = ((size_t)b * 4 + ho) * 64 + w0;

    for (int i = 0; i < 32; ++i)
        lds[i * 257 + tid] = C2[(rbase + i) * COd + tid];
    __syncthreads();

    int wv = tid >> 6, lane = tid & 63;
    for (int rr = 0; rr < 8; ++rr) {
        int i = wv * 8 + rr;
        float v0 = lds[i*257 + lane], v1 = lds[i*257 + lane + 64];
        float v2 = lds[i*257 + lane + 128], v3 = lds[i*257 + lane + 192];
        float s = v0 + v1 + v2 + v3;
        #pragma unroll
        for (int off = 32; off > 0; off >>= 1) s += __shfl_xor(s, off);
        float mu = s * (1.f / 256.f);
        float d0 = v0-mu, d1 = v1-mu, d2 = v2-mu, d3 = v3-mu;
        float qv = d0*d0 + d1*d1 + d2*d2 + d3*d3;
        #pragma unroll
        for (int off = 32; off > 0; off >>= 1) qv += __shfl_xor(qv, off);
        float rstd = rsqrtf(qv * (1.f / 256.f) + 1e-5f);
        lds[i*257 + lane]       = d0 * rstd * g[lane]       + beta[lane];
        lds[i*257 + lane + 64]  = d1 * rstd * g[lane + 64]  + beta[lane + 64];
        lds[i*257 + lane + 128] = d2 * rstd * g[lane + 128] + beta[lane + 128];
        lds[i*257 + lane + 192] = d3 * rstd * g[lane + 192] + beta[lane + 192];
    }
    __syncthreads();

    int w = tid & 31, half = tid >> 5;
    for (int j = 0; j < 32; ++j) {
        int co = half + j * 8;
        out[(((size_t)b * COd + co) * 4 + ho) * Wimg + w0 + w] = lds[w * 257 + co];
    }
}

// ---------------------------------------------------------------------------
extern "C" void kernel_launch(void* const* d_in, const int* in_sizes, int n_in,
                              void* d_out, int out_size, void* d_ws, size_t ws_size,
                              hipStream_t stream) {
    const float* image = (const float*)d_in[0];
    const float* in_w  = (const float*)d_in[1];
    const float* in_b  = (const float*)d_in[2];
    const float* out_w = (const float*)d_in[3];
    const float* out_b = (const float*)d_in[4];
    const float* ln1_g = (const float*)d_in[5];
    const float* ln1_b = (const float*)d_in[6];
    const float* ln2_g = (const float*)d_in[7];
    const float* ln2_b = (const float*)d_in[8];
    const float* w1    = (const float*)d_in[9];
    const float* b1    = (const float*)d_in[10];
    const float* w2    = (const float*)d_in[11];
    const float* b2    = (const float*)d_in[12];
    const float* convw = (const float*)d_in[13];
    const float* convb = (const float*)d_in[14];
    const float* mln_g = (const float*)d_in[15];
    const float* mln_b = (const float*)d_in[16];
    float* out = (float*)d_out;
    float* ws  = (float*)d_ws;

    // ws layout (float units):
    //  X    [0, 6291456)
    //  XN   [6291456, 12582912)
    //  BIG  [12582912, 28311552):
    //       QP bf16 @BIG (3145728 f) | KP @+3145728 | VT @+6291456
    //       Hb bf16 (12582912 f, clobbers QP/KP/VT after attention)
    //       A2b bf16 @BIG + C2 f32 @BIG+4718592 (conv path, end)
    //  XNb  bf16 @ BIG+12582912  [25165824, 28311552)
    //  ATTb bf16 [28311552, 31457280)
    //  Wb   bf16 [31457280, 32858112)
    float* X    = ws;
    float* XN   = ws + 6291456;
    float* BIG  = ws + 12582912;
    ushort* QP   = (ushort*)BIG;
    ushort* KP   = (ushort*)(BIG + 3145728);
    ushort* VT   = (ushort*)(BIG + 6291456);
    ushort* Hb   = (ushort*)BIG;
    ushort* A2b  = (ushort*)BIG;
    float*  C2   = BIG + 4718592;
    ushort* XNb  = (ushort*)(BIG + 12582912);
    ushort* ATTb = (ushort*)(ws + 28311552);
    ushort* Wb   = (ushort*)(ws + 31457280);

    ushort* in_wb  = Wb;                    // 663552
    ushort* out_wb = Wb + 663552;           // 221184
    ushort* w1b    = Wb + 884736;           // 884736
    ushort* w2b    = Wb + 1769472;          // 884736
    ushort* cwb    = Wb + 2654208;          // 147456

    reshape_in<<<Mrows * Ed / 256, 256, 0, stream>>>(image, X);
    f2b_arr<<<(663552 + 255) / 256, 256, 0, stream>>>(in_w,  in_wb,  663552);
    f2b_arr<<<(221184 + 255) / 256, 256, 0, stream>>>(out_w, out_wb, 221184);
    f2b_arr<<<(884736 + 255) / 256, 256, 0, stream>>>(w1,    w1b,    884736);
    f2b_arr<<<(884736 + 255) / 256, 256, 0, stream>>>(w2,    w2b,    884736);
    conv_w_to_bf16<<<(147456 + 255) / 256, 256, 0, stream>>>(convw, cwb);

    for (int i = 0; i < Ld; ++i) {
        ln_kernel<<<Mrows / 4, 256, 0, stream>>>(X, XN, XNb, ln1_g + i*Ed, ln1_b + i*Ed);
        // QKV: M=32768, N=576 (9 col-chunks), K=192
        gemm_reg<1,0,0,1,1><<<(Mrows/64)*9/4, 256, 0, stream>>>(
            XNb, in_wb + (size_t)i * 3*Ed*Ed, in_b + i * 3*Ed,
            nullptr, nullptr, nullptr, QP, KP, VT, Mrows, 3*Ed, 9);
        if (i >= 2) attn_mfma<1><<<dim3(Bn * NHd, 8), 256, 0, stream>>>(QP, KP, VT, ATTb);
        else        attn_mfma<0><<<dim3(Bn * NHd, 8), 256, 0, stream>>>(QP, KP, VT, ATTb);
        // out-proj: N=192 (3 chunks), K=192, +resid -> X fp32
        gemm_reg<1,0,1,0,0><<<(Mrows/64)*3/4, 256, 0, stream>>>(
            ATTb, out_wb + (size_t)i * Ed*Ed, out_b + i*Ed,
            XN, X, nullptr, nullptr, nullptr, nullptr, Mrows, Ed, 3);
        ln_kernel<<<Mrows / 4, 256, 0, stream>>>(X, XN, XNb, ln2_g + i*Ed, ln2_b + i*Ed);
        // mlp1: N=768 (12 chunks), K=192, relu -> Hb bf16
        gemm_reg<1,1,0,1,0><<<(Mrows/64)*12/4, 256, 0, stream>>>(
            XNb, w1b + (size_t)i * 4*Ed*Ed, b1 + i * 4*Ed,
            nullptr, nullptr, Hb, nullptr, nullptr, nullptr, Mrows, 4*Ed, 12);
        // mlp2: N=192 (3 chunks), K=768 (4 kchunks), +resid -> X fp32
        gemm_reg<4,0,1,0,0><<<(Mrows/64)*3/4, 256, 0, stream>>>(
            Hb, w2b + (size_t)i * 4*Ed*Ed, b2 + i*Ed,
            XN, X, nullptr, nullptr, nullptr, nullptr, Mrows, Ed, 3);
    }

    im2col<<<9437184 / 256, 256, 0, stream>>>(X, A2b);
    // conv: M=16384, N=256 (4 chunks), K=576 (3 kchunks) -> C2 fp32
    gemm_reg<3,0,0,0,0><<<(16384/64)*4/4, 256, 0, stream>>>(
        A2b, cwb, convb, nullptr, C2, nullptr, nullptr, nullptr, nullptr,
        16384, COd, 4);
    ln_out_kernel<<<dim3(2, 4, Bn), 256, 0, stream>>>(C2, mln_g, mln_b, out);
}

// Round 8
// 1107.724 us; speedup vs baseline: 1.4433x; 1.4433x over previous
//
#include <hip/hip_runtime.h>
#include <hip/hip_bf16.h>
#include <math.h>

// Problem constants
#define Bn   64
#define Ssz  512     // W*H = 64*8
#define Ed   192
#define NHd  6
#define HDd  32
#define Ld   6
#define COd  256
#define Himg 8
#define Wimg 64
#define Mrows (Bn*Ssz)   // 32768

typedef unsigned int  uint;
typedef unsigned short ushort;
using short8 = __attribute__((ext_vector_type(8))) short;
using f32x4  = __attribute__((ext_vector_type(4))) float;

#define WAIT_LGKM() __asm__ __volatile__("s_waitcnt lgkmcnt(0)" ::: "memory")

__device__ inline ushort f2b(float f) {          // fp32 -> bf16 RNE
    uint u = __builtin_bit_cast(uint, f);
    u = (u + 0x7FFFu + ((u >> 16) & 1u)) >> 16;
    return (ushort)u;
}

__device__ __forceinline__ float fexp2(float x) {
#if __has_builtin(__builtin_amdgcn_exp2f)
    return __builtin_amdgcn_exp2f(x);
#else
    return exp2f(x);
#endif
}

// async global->LDS 16B: lane i lands at lds + i*16 (wave-uniform lds base)
__device__ __forceinline__ void gload16(const ushort* g, ushort* l, int lane) {
#if __has_builtin(__builtin_amdgcn_global_load_lds)
    __builtin_amdgcn_global_load_lds(
        (const __attribute__((address_space(1))) uint*)g,
        (__attribute__((address_space(3))) uint*)l, 16, 0, 0);
#else
    *(uint4*)(l + (size_t)lane * 8) = *(const uint4*)g;
#endif
}

// ---------------------------------------------------------------------------
// reshape: image [B, E, 8, 64] -> X [B, S=w*8+h, E]  (fp32)
__global__ __launch_bounds__(256) void reshape_in(const float* __restrict__ img,
                                                  float* __restrict__ X) {
    int t = blockIdx.x * 256 + threadIdx.x;
    int c = t % Ed;
    int s = (t / Ed) % Ssz;
    int b = t / (Ed * Ssz);
    int w = s >> 3, h = s & 7;
    X[t] = img[(((size_t)b * Ed + c) * Himg + h) * Wimg + w];
}

// ---------------------------------------------------------------------------
__global__ __launch_bounds__(256) void f2b_arr(const float* __restrict__ in,
                                               ushort* __restrict__ out, int n) {
    int t = blockIdx.x * 256 + threadIdx.x;
    if (t < n) out[t] = f2b(in[t]);
}

// conv_w [CO,E,3,1] -> bf16 layout [co][kh*192+c]
__global__ __launch_bounds__(256) void conv_w_to_bf16(const float* __restrict__ cw,
                                                      ushort* __restrict__ out) {
    int t = blockIdx.x * 256 + threadIdx.x;
    if (t >= COd * 576) return;
    int co = t / 576, rem = t % 576;
    int kh = rem / Ed, c = rem % Ed;
    out[t] = f2b(cw[((size_t)co * Ed + c) * 3 + kh]);
}

// ---------------------------------------------------------------------------
// LayerNorm over E=192 (only used once, after reshape).
__global__ __launch_bounds__(256) void ln_kernel(const float* __restrict__ in,
                                                 float* __restrict__ out,
                                                 ushort* __restrict__ outb,
                                                 const float* __restrict__ g,
                                                 const float* __restrict__ bb) {
    int row  = blockIdx.x * 4 + (threadIdx.x >> 6);
    int lane = threadIdx.x & 63;
    bool act = lane < 48;
    float4 v = make_float4(0.f, 0.f, 0.f, 0.f);
    if (act) v = ((const float4*)(in + (size_t)row * Ed))[lane];
    float s = v.x + v.y + v.z + v.w;
    #pragma unroll
    for (int off = 32; off > 0; off >>= 1) s += __shfl_xor(s, off);
    float mu = s * (1.f / 192.f);
    float4 d = make_float4(v.x - mu, v.y - mu, v.z - mu, v.w - mu);
    float qv = act ? (d.x*d.x + d.y*d.y + d.z*d.z + d.w*d.w) : 0.f;
    #pragma unroll
    for (int off = 32; off > 0; off >>= 1) qv += __shfl_xor(qv, off);
    float rstd = rsqrtf(qv * (1.f / 192.f) + 1e-5f);
    if (act) {
        float4 gg  = ((const float4*)g)[lane];
        float4 bbv = ((const float4*)bb)[lane];
        float4 y = make_float4(d.x * rstd * gg.x + bbv.x,
                               d.y * rstd * gg.y + bbv.y,
                               d.z * rstd * gg.z + bbv.z,
                               d.w * rstd * gg.w + bbv.w);
        ((float4*)(out + (size_t)row * Ed))[lane] = y;
        ushort4 yb;
        yb.x = f2b(y.x); yb.y = f2b(y.y); yb.z = f2b(y.z); yb.w = f2b(y.w);
        *(ushort4*)(outb + (size_t)row * Ed + lane * 4) = yb;
    }
}

// ---------------------------------------------------------------------------
// bf16 MFMA GEMM (round-6 structure): BM=128 BN=64 BK=96; 256 thr / 4 waves.
// VOUT: Q cols -> QP[bh][s][32], K cols -> KP[bh][s][32], V cols -> VT[bh][d][s].
template<int RELU, int RESID, int OBF, int VOUT>
__global__ __launch_bounds__(256) void gemm_mfma(
    const ushort* __restrict__ A, const ushort* __restrict__ Wt,
    const float* __restrict__ bias, const float* __restrict__ resid,
    float* __restrict__ C, ushort* __restrict__ Cb,
    ushort* __restrict__ qpout, ushort* __restrict__ kpout,
    ushort* __restrict__ vtout,
    int M, int N, int K)
{
    __shared__ __align__(16) ushort As[12288];   // 24 frags (8 msub x 3 ksub) * 1KB
    __shared__ __align__(16) ushort Bs[6144];    // 12 frags (4 nsub x 3 ksub) * 1KB
    const int tid  = threadIdx.x;
    const int lane = tid & 63;
    const int wave = tid >> 6;
    const int wr = wave >> 1, wc = wave & 1;
    const int bm = blockIdx.x * 128;
    const int bn = blockIdx.y * 64;

    const ushort* Ag[6]; ushort* Al[6];
    #pragma unroll
    for (int i = 0; i < 6; ++i) {
        int fa = 4 * i + wave;                 // 0..23
        int msub = fa / 3, ksub = fa % 3;
        int m = msub * 16 + (lane & 15);
        int k = ksub * 32 + ((lane >> 4) << 3);
        Ag[i] = A + (size_t)(bm + m) * K + k;
        Al[i] = As + fa * 512;                 // wave-uniform
    }
    const ushort* Bg[3]; ushort* Bl[3];
    #pragma unroll
    for (int i = 0; i < 3; ++i) {
        int fb = 4 * i + wave;                 // 0..11
        int nsub = fb / 3, ksub = fb % 3;
        int n = nsub * 16 + (lane & 15);
        int k = ksub * 32 + ((lane >> 4) << 3);
        Bg[i] = Wt + (size_t)(bn + n) * K + k;
        Bl[i] = Bs + fb * 512;
    }

    f32x4 acc[4][2];
    #pragma unroll
    for (int i = 0; i < 4; ++i)
        #pragma unroll
        for (int j = 0; j < 2; ++j) acc[i][j] = (f32x4){0.f, 0.f, 0.f, 0.f};

    for (int k0 = 0; k0 < K; k0 += 96) {
        #pragma unroll
        for (int i = 0; i < 6; ++i) gload16(Ag[i] + k0, Al[i], lane);
        #pragma unroll
        for (int i = 0; i < 3; ++i) gload16(Bg[i] + k0, Bl[i], lane);
        __syncthreads();
        #pragma unroll
        for (int ksub = 0; ksub < 3; ++ksub) {
            short8 af[4], bf[2];
            #pragma unroll
            for (int ms = 0; ms < 4; ++ms)
                af[ms] = *(const short8*)(As + (((wr*4+ms)*3 + ksub) * 64 + lane) * 8);
            #pragma unroll
            for (int ns = 0; ns < 2; ++ns)
                bf[ns] = *(const short8*)(Bs + (((wc*2+ns)*3 + ksub) * 64 + lane) * 8);
            #pragma unroll
            for (int ms = 0; ms < 4; ++ms)
                #pragma unroll
                for (int ns = 0; ns < 2; ++ns)
                    acc[ms][ns] = __builtin_amdgcn_mfma_f32_16x16x32_bf16(
                        af[ms], bf[ns], acc[ms][ns], 0, 0, 0);
        }
        __syncthreads();
    }

    int q = lane >> 4, colL = lane & 15;
    #pragma unroll
    for (int ms = 0; ms < 4; ++ms) {
        #pragma unroll
        for (int ns = 0; ns < 2; ++ns) {
            int row0 = bm + (wr*4 + ms) * 16 + q * 4;
            int col  = bn + (wc*2 + ns) * 16 + colL;
            float bvv = bias[col];
            float v[4];
            #pragma unroll
            for (int r = 0; r < 4; ++r) {
                v[r] = acc[ms][ns][r] + bvv;
                if (RELU) v[r] = fmaxf(v[r], 0.f);
                if (RESID) v[r] += resid[(size_t)(row0 + r) * N + col];
            }
            if (VOUT) {
                int bidx = row0 >> 9, srow = row0 & 511;
                if (col >= 384) {                 // V -> VT[bh][d][s]
                    int hh = (col - 384) >> 5, dd = (col - 384) & 31;
                    ushort4 pv;
                    pv.x = f2b(v[0]); pv.y = f2b(v[1]); pv.z = f2b(v[2]); pv.w = f2b(v[3]);
                    *(ushort4*)(vtout + (((size_t)(bidx * NHd + hh) * 32 + dd) << 9) + srow) = pv;
                } else {                          // Q/K -> {QP,KP}[bh][s][32]
                    ushort* dst = (col < 192) ? qpout : kpout;
                    int cc = (col < 192) ? col : col - 192;
                    int hh = cc >> 5, dd = cc & 31;
                    ushort* p = dst + ((size_t)(bidx * NHd + hh) << 14) + (size_t)srow * 32 + dd;
                    p[0]  = f2b(v[0]); p[32] = f2b(v[1]);
                    p[64] = f2b(v[2]); p[96] = f2b(v[3]);
                }
            } else {
                #pragma unroll
                for (int r = 0; r < 4; ++r) {
                    if (OBF) Cb[(size_t)(row0 + r) * N + col] = f2b(v[r]);
                    else     C [(size_t)(row0 + r) * N + col] = v[r];
                }
            }
        }
    }
}

// ---------------------------------------------------------------------------
// Fused GEMM (+bias +resid) + row LayerNorm. N=192 fixed (full row per block).
// BM=64, BN=192, BK=64, 256 thr / 4 waves; wave owns 16 rows x 192 cols, so
// mean/var reduce is 4 quad-local shfls. K = KIT*64.
// LNOUT=1: write LN output (fp32 outf + bf16 outb). LNOUT=0: plain fp32.
template<int KIT, int LNOUT>
__global__ __launch_bounds__(256) void gemm_ln(
    const ushort* __restrict__ A, const ushort* __restrict__ Wt,
    const float* __restrict__ bias, const float* __restrict__ resid,
    const float* __restrict__ lng, const float* __restrict__ lnb,
    float* __restrict__ outf, ushort* __restrict__ outb)
{
    __shared__ __align__(16) ushort As[4096];    // 8 frags (4 msub x 2 ksub)
    __shared__ __align__(16) ushort Bs[12288];   // 24 frags (12 nsub x 2 ksub)
    const int K = KIT * 64;
    const int lane = threadIdx.x & 63;
    const int wave = threadIdx.x >> 6;
    const int g = lane >> 4, ql = lane & 15;
    const int bm = blockIdx.x * 64;

    const ushort* Gp[8]; ushort* Lp[8];
    #pragma unroll
    for (int i = 0; i < 8; ++i) {
        int f = 4 * i + wave;                    // 0..31
        if (f < 8) {
            int msub = f >> 1, ksub = f & 1;
            Gp[i] = A + (size_t)(bm + msub * 16 + ql) * K + ksub * 32 + g * 8;
            Lp[i] = As + f * 512;
        } else {
            int fb = f - 8, nsub = fb >> 1, ksub = fb & 1;
            Gp[i] = Wt + (size_t)(nsub * 16 + ql) * K + ksub * 32 + g * 8;
            Lp[i] = Bs + fb * 512;
        }
    }

    f32x4 acc[12];
    #pragma unroll
    for (int i = 0; i < 12; ++i) acc[i] = (f32x4){0.f, 0.f, 0.f, 0.f};

    for (int kc = 0; kc < KIT; ++kc) {
        #pragma unroll
        for (int i = 0; i < 8; ++i) gload16(Gp[i] + kc * 64, Lp[i], lane);
        __syncthreads();
        #pragma unroll
        for (int ksub = 0; ksub < 2; ++ksub) {
            short8 af = *(const short8*)(As + ((wave * 2 + ksub) * 64 + lane) * 8);
            #pragma unroll
            for (int ns = 0; ns < 12; ++ns) {
                short8 bf = *(const short8*)(Bs + ((ns * 2 + ksub) * 64 + lane) * 8);
                acc[ns] = __builtin_amdgcn_mfma_f32_16x16x32_bf16(af, bf, acc[ns], 0, 0, 0);
            }
        }
        __syncthreads();
    }

    float bi[12], gg[12], bb[12];
    #pragma unroll
    for (int ns = 0; ns < 12; ++ns) {
        int col = ns * 16 + ql;
        bi[ns] = bias[col];
        if (LNOUT) { gg[ns] = lng[col]; bb[ns] = lnb[col]; }
    }
    #pragma unroll
    for (int r = 0; r < 4; ++r) {
        int row = bm + wave * 16 + g * 4 + r;
        float v[12];
        #pragma unroll
        for (int ns = 0; ns < 12; ++ns)
            v[ns] = acc[ns][r] + bi[ns] + resid[(size_t)row * Ed + ns * 16 + ql];
        if (LNOUT) {
            float s = 0.f;
            #pragma unroll
            for (int ns = 0; ns < 12; ++ns) s += v[ns];
            s += __shfl_xor(s, 1); s += __shfl_xor(s, 2);
            s += __shfl_xor(s, 4); s += __shfl_xor(s, 8);
            float mu = s * (1.f / 192.f);
            float qv = 0.f;
            #pragma unroll
            for (int ns = 0; ns < 12; ++ns) { float d = v[ns] - mu; qv += d * d; }
            qv += __shfl_xor(qv, 1); qv += __shfl_xor(qv, 2);
            qv += __shfl_xor(qv, 4); qv += __shfl_xor(qv, 8);
            float rstd = rsqrtf(qv * (1.f / 192.f) + 1e-5f);
            #pragma unroll
            for (int ns = 0; ns < 12; ++ns) {
                float y = (v[ns] - mu) * rstd * gg[ns] + bb[ns];
                int col = ns * 16 + ql;
                outf[(size_t)row * Ed + col] = y;
                outb[(size_t)row * Ed + col] = f2b(y);
            }
        } else {
            #pragma unroll
            for (int ns = 0; ns < 12; ++ns)
                outf[(size_t)row * Ed + ns * 16 + ql] = v[ns];
        }
    }
}

// ---------------------------------------------------------------------------
// MFMA attention, 2 q-tiles per wave (32 q x 512 keys): K/V loads shared
// across tiles. Unshifted softmax via exp2; denominator via ones-MFMA.
// grid (384 bh, 4); block 256 = 4 waves x 32 q = 128 q.
template<int USE_MASK>
__global__ __launch_bounds__(256) void attn_mfma(const ushort* __restrict__ qp,
                                                 const ushort* __restrict__ kp,
                                                 const ushort* __restrict__ vt,
                                                 ushort* __restrict__ att) {
    __shared__ __align__(16) ushort P[4][4][2][512];   // 32 KB
    const int bh = blockIdx.x;
    const int b = bh / NHd, h = bh % NHd;
    const int wave = threadIdx.x >> 6, lane = threadIdx.x & 63;
    const int g = lane >> 4, ql = lane & 15;
    const int qb = blockIdx.y * 128 + wave * 32;
    const float c2 = 0.2550547270628364f; // log2(e)/sqrt(32)

    const ushort* qbase = qp + ((size_t)bh << 14);
    const ushort* kbase = kp + ((size_t)bh << 14);
    const ushort* vbase = vt + ((size_t)bh << 14);
    short8 qf[2];
    #pragma unroll
    for (int t = 0; t < 2; ++t)
        qf[t] = *(const short8*)(qbase + (size_t)(qb + t * 16 + ql) * 32 + g * 8);
    ushort* pw = &P[wave][0][0][0];

    short8 onesf;
    #pragma unroll
    for (int j = 0; j < 8; ++j) onesf[j] = (short)0x3F80;   // bf16 1.0

    uint m0[2], m1[2]; int qh[2];
    if (USE_MASK) {
        #pragma unroll
        for (int t = 0; t < 2; ++t) {
            int qwt = ((qb + t * 16) & 63) + ql;      // no wrap: base%16==0
            qh[t] = (qb + t * 16) >> 6;
            uint a0 = 0, a1 = 0;
            #pragma unroll
            for (int i = 0; i < 8; ++i) {
                int keyl = (i >> 2) * 16 + 4 * g + (i & 3);
                int d0 = keyl - qwt;      d0 = d0 < 0 ? -d0 : d0;
                int d1 = keyl + 32 - qwt; d1 = d1 < 0 ? -d1 : d1;
                if (d0 <= 5) a0 |= (1u << i);
                if (d1 <= 5) a1 |= (1u << i);
            }
            m0[t] = a0; m1[t] = a1;
        }
    }

    f32x4 o0[2], o1[2], o2[2];
    #pragma unroll
    for (int t = 0; t < 2; ++t) {
        o0[t] = (f32x4){0.f,0.f,0.f,0.f};
        o1[t] = (f32x4){0.f,0.f,0.f,0.f};
        o2[t] = (f32x4){0.f,0.f,0.f,0.f};
    }
    const f32x4 z = {0.f,0.f,0.f,0.f};
    const int wst0 = ((g >> 1) * 16 + ql) * 8 + (g & 1) * 4;
    const int wst1 = (((g >> 1) + 2) * 16 + ql) * 8 + (g & 1) * 4;

    for (int grp = 0; grp < 4; ++grp) {
        #pragma unroll
        for (int c = 0; c < 4; ++c) {
            const int kt = grp * 4 + c;
            const int kb = kt * 32;
            short8 kf0 = *(const short8*)(kbase + (size_t)(kb + ql) * 32 + g * 8);
            short8 kf1 = *(const short8*)(kbase + (size_t)(kb + 16 + ql) * 32 + g * 8);
            #pragma unroll
            for (int t = 0; t < 2; ++t) {
                f32x4 st0 = __builtin_amdgcn_mfma_f32_16x16x32_bf16(kf0, qf[t], z, 0, 0, 0);
                f32x4 st1 = __builtin_amdgcn_mfma_f32_16x16x32_bf16(kf1, qf[t], z, 0, 0, 0);
                float p[8];
                #pragma unroll
                for (int r = 0; r < 4; ++r) {
                    p[r]     = fexp2(st0[r] * c2);
                    p[4 + r] = fexp2(st1[r] * c2);
                }
                if (USE_MASK) {
                    int dh = (kt >> 1) - qh[t]; dh = dh < 0 ? -dh : dh;
                    if (dh <= 3) {
                        uint mm = (kt & 1) ? m1[t] : m0[t];
                        #pragma unroll
                        for (int i = 0; i < 8; ++i)
                            if ((mm >> i) & 1u) p[i] = 0.f;
                    }
                }
                uint u[8];
                #pragma unroll
                for (int i = 0; i < 8; ++i) u[i] = __builtin_bit_cast(uint, p[i]) + 0x8000u;
                uint2 w0, w1;
                w0.x = __builtin_amdgcn_perm(u[1], u[0], 0x07060302u);
                w0.y = __builtin_amdgcn_perm(u[3], u[2], 0x07060302u);
                w1.x = __builtin_amdgcn_perm(u[5], u[4], 0x07060302u);
                w1.y = __builtin_amdgcn_perm(u[7], u[6], 0x07060302u);
                *(uint2*)(pw + (c * 2 + t) * 512 + wst0) = w0;
                *(uint2*)(pw + (c * 2 + t) * 512 + wst1) = w1;
            }
        }
        WAIT_LGKM();
        #pragma unroll
        for (int c = 0; c < 4; ++c) {
            const int kb = (grp * 4 + c) * 32;
            short8 vf0 = *(const short8*)(vbase + (size_t)ql * 512 + kb + 8 * g);
            short8 vf1 = *(const short8*)(vbase + (size_t)(16 + ql) * 512 + kb + 8 * g);
            #pragma unroll
            for (int t = 0; t < 2; ++t) {
                short8 paf = *(const short8*)(pw + (c * 2 + t) * 512 + lane * 8);
                o0[t] = __builtin_amdgcn_mfma_f32_16x16x32_bf16(paf, vf0, o0[t], 0, 0, 0);
                o1[t] = __builtin_amdgcn_mfma_f32_16x16x32_bf16(paf, vf1, o1[t], 0, 0, 0);
                o2[t] = __builtin_amdgcn_mfma_f32_16x16x32_bf16(paf, onesf, o2[t], 0, 0, 0);
            }
        }
        WAIT_LGKM();
    }
    ushort* op = att + (size_t)b * Ssz * Ed + h * 32;
    #pragma unroll
    for (int t = 0; t < 2; ++t) {
        #pragma unroll
        for (int r = 0; r < 4; ++r) {
            float iv = 1.f / o2[t][r];
            int row = qb + t * 16 + 4 * g + r;
            op[(size_t)row * Ed + ql]      = f2b(o0[t][r] * iv);
            op[(size_t)row * Ed + 16 + ql] = f2b(o1[t][r] * iv);
        }
    }
}

// ---------------------------------------------------------------------------
// im2col for merging conv: A2[r=(b*4+ho)*64+w][kh*192+c] = X[b, w*8+2ho+kh-1, c]
__global__ __launch_bounds__(256) void im2col(const float* __restrict__ X,
                                              ushort* __restrict__ A2) {
    int t = blockIdx.x * 256 + threadIdx.x;      // 9437184
    int col = t % 576;
    int r   = t / 576;
    int kh = col / Ed, c = col % Ed;
    int w = r & 63, ho = (r >> 6) & 3, b = r >> 8;
    int hin = 2 * ho + kh - 1;
    float v = 0.f;
    if (hin >= 0 && hin < Himg)
        v = X[((size_t)(b * Ssz + w * Himg + hin)) * Ed + c];
    A2[t] = f2b(v);
}

// ---------------------------------------------------------------------------
// channel LN on conv output C2[r=(b*4+ho)*64+w][co=256] -> out[b,co,ho,w]
__global__ __launch_bounds__(256) void ln_out_kernel(const float* __restrict__ C2,
                                                     const float* __restrict__ g,
                                                     const float* __restrict__ beta,
                                                     float* __restrict__ out) {
    __shared__ float lds[32 * 257];
    int w0 = blockIdx.x * 32, ho = blockIdx.y, b = blockIdx.z;
    int tid = threadIdx.x;
    size_t rbase = ((size_t)b * 4 + ho) * 64 + w0;

    for (int i = 0; i < 32; ++i)
        lds[i * 257 + tid] = C2[(rbase + i) * COd + tid];
    __syncthreads();

    int wv = tid >> 6, lane = tid & 63;
    for (int rr = 0; rr < 8; ++rr) {
        int i = wv * 8 + rr;
        float v0 = lds[i*257 + lane], v1 = lds[i*257 + lane + 64];
        float v2 = lds[i*257 + lane + 128], v3 = lds[i*257 + lane + 192];
        float s = v0 + v1 + v2 + v3;
        #pragma unroll
        for (int off = 32; off > 0; off >>= 1) s += __shfl_xor(s, off);
        float mu = s * (1.f / 256.f);
        float d0 = v0-mu, d1 = v1-mu, d2 = v2-mu, d3 = v3-mu;
        float qv = d0*d0 + d1*d1 + d2*d2 + d3*d3;
        #pragma unroll
        for (int off = 32; off > 0; off >>= 1) qv += __shfl_xor(qv, off);
        float rstd = rsqrtf(qv * (1.f / 256.f) + 1e-5f);
        lds[i*257 + lane]       = d0 * rstd * g[lane]       + beta[lane];
        lds[i*257 + lane + 64]  = d1 * rstd * g[lane + 64]  + beta[lane + 64];
        lds[i*257 + lane + 128] = d2 * rstd * g[lane + 128] + beta[lane + 128];
        lds[i*257 + lane + 192] = d3 * rstd * g[lane + 192] + beta[lane + 192];
    }
    __syncthreads();

    int w = tid & 31, half = tid >> 5;
    for (int j = 0; j < 32; ++j) {
        int co = half + j * 8;
        out[(((size_t)b * COd + co) * 4 + ho) * Wimg + w0 + w] = lds[w * 257 + co];
    }
}

// ---------------------------------------------------------------------------
extern "C" void kernel_launch(void* const* d_in, const int* in_sizes, int n_in,
                              void* d_out, int out_size, void* d_ws, size_t ws_size,
                              hipStream_t stream) {
    const float* image = (const float*)d_in[0];
    const float* in_w  = (const float*)d_in[1];
    const float* in_b  = (const float*)d_in[2];
    const float* out_w = (const float*)d_in[3];
    const float* out_b = (const float*)d_in[4];
    const float* ln1_g = (const float*)d_in[5];
    const float* ln1_b = (const float*)d_in[6];
    const float* ln2_g = (const float*)d_in[7];
    const float* ln2_b = (const float*)d_in[8];
    const float* w1    = (const float*)d_in[9];
    const float* b1    = (const float*)d_in[10];
    const float* w2    = (const float*)d_in[11];
    const float* b2    = (const float*)d_in[12];
    const float* convw = (const float*)d_in[13];
    const float* convb = (const float*)d_in[14];
    const float* mln_g = (const float*)d_in[15];
    const float* mln_b = (const float*)d_in[16];
    float* out = (float*)d_out;
    float* ws  = (float*)d_ws;

    // ws layout (float units):
    //  F1 (x1 stream fp32)   [0, 6291456)
    //  F2 (x3 stream fp32)   [6291456, 12582912)   (also reshape landing pad)
    //  BIG [12582912, 28311552):
    //       QP bf16 @BIG | KP @+3145728 | VT @+6291456
    //       Hb bf16 (clobbers QP/KP/VT after attention)
    //       A2b bf16 @BIG + C2 f32 @BIG+4718592 (conv path, end)
    //  XNb  bf16 @ BIG+12582912  [25165824, 28311552)
    //  ATTb bf16 [28311552, 31457280)
    //  Wb   bf16 [31457280, 32858112)
    float* F1   = ws;
    float* F2   = ws + 6291456;
    float* BIG  = ws + 12582912;
    ushort* QP   = (ushort*)BIG;
    ushort* KP   = (ushort*)(BIG + 3145728);
    ushort* VT   = (ushort*)(BIG + 6291456);
    ushort* Hb   = (ushort*)BIG;
    ushort* A2b  = (ushort*)BIG;
    float*  C2   = BIG + 4718592;
    ushort* XNb  = (ushort*)(BIG + 12582912);
    ushort* ATTb = (ushort*)(ws + 28311552);
    ushort* Wb   = (ushort*)(ws + 31457280);

    ushort* in_wb  = Wb;                    // 663552
    ushort* out_wb = Wb + 663552;           // 221184
    ushort* w1b    = Wb + 884736;           // 884736
    ushort* w2b    = Wb + 1769472;          // 884736
    ushort* cwb    = Wb + 2654208;          // 147456

    reshape_in<<<Mrows * Ed / 256, 256, 0, stream>>>(image, F2);
    f2b_arr<<<(663552 + 255) / 256, 256, 0, stream>>>(in_w,  in_wb,  663552);
    f2b_arr<<<(221184 + 255) / 256, 256, 0, stream>>>(out_w, out_wb, 221184);
    f2b_arr<<<(884736 + 255) / 256, 256, 0, stream>>>(w1,    w1b,    884736);
    f2b_arr<<<(884736 + 255) / 256, 256, 0, stream>>>(w2,    w2b,    884736);
    conv_w_to_bf16<<<(147456 + 255) / 256, 256, 0, stream>>>(convw, cwb);

    // layer-0 LN1: F2(raw) -> F1 (x1 fp32) + XNb (x1 bf16)
    ln_kernel<<<Mrows / 4, 256, 0, stream>>>(F2, F1, XNb, ln1_g, ln1_b);

    for (int i = 0; i < Ld; ++i) {
        gemm_mfma<0,0,1,1><<<dim3(Mrows/128, 9), 256, 0, stream>>>(
            XNb, in_wb + (size_t)i * 3*Ed*Ed, in_b + i * 3*Ed,
            nullptr, nullptr, nullptr, QP, KP, VT, Mrows, 3*Ed, Ed);
        if (i >= 2) attn_mfma<1><<<dim3(Bn * NHd, 4), 256, 0, stream>>>(QP, KP, VT, ATTb);
        else        attn_mfma<0><<<dim3(Bn * NHd, 4), 256, 0, stream>>>(QP, KP, VT, ATTb);
        // out-proj + x1 + LN2 -> F2 (x3 fp32) + XNb (x3 bf16)
        gemm_ln<3,1><<<Mrows/64, 256, 0, stream>>>(
            ATTb, out_wb + (size_t)i * Ed*Ed, out_b + i*Ed,
            F1, ln2_g + i*Ed, ln2_b + i*Ed, F2, XNb);
        gemm_mfma<1,0,1,0><<<dim3(Mrows/128, 12), 256, 0, stream>>>(
            XNb, w1b + (size_t)i * 4*Ed*Ed, b1 + i * 4*Ed,
            nullptr, nullptr, Hb, nullptr, nullptr, nullptr, Mrows, 4*Ed, Ed);
        if (i < Ld - 1) {
            // mlp2 + x3 + LN1(next) -> F1 (x1' fp32) + XNb (x1' bf16)
            gemm_ln<12,1><<<Mrows/64, 256, 0, stream>>>(
                Hb, w2b + (size_t)i * 4*Ed*Ed, b2 + i*Ed,
                F2, ln1_g + (i+1)*Ed, ln1_b + (i+1)*Ed, F1, XNb);
        } else {
            // last layer: mlp2 + x3 -> F1 (x4 fp32, conv input)
            gemm_ln<12,0><<<Mrows/64, 256, 0, stream>>>(
                Hb, w2b + (size_t)i * 4*Ed*Ed, b2 + i*Ed,
                F2, nullptr, nullptr, F1, nullptr);
        }
    }

    im2col<<<9437184 / 256, 256, 0, stream>>>(F1, A2b);
    gemm_mfma<0,0,0,0><<<dim3(16384/128, 4), 256, 0, stream>>>(
        A2b, cwb, convb, nullptr, C2, nullptr, nullptr, nullptr, nullptr,
        16384, COd, 576);
    ln_out_kernel<<<dim3(2, 4, Bn), 256, 0, stream>>>(C2, mln_g, mln_b, out);
}